// Round 5
// baseline (303.393 us; speedup 1.0000x reference)
//
#include <hip/hip_runtime.h>
#include <math.h>

#define DIM    512
#define HEADS  8
#define DK     32
#define NKEYS  256
#define PKTOP  16
#define NTOK   1024   // b*n = 2*512

// gelu (tanh approx, matches flax approximate gelu)
__device__ __forceinline__ float gelu_t(float x)
{
    float x3 = x * x * x;
    return 0.5f * x * (1.f + tanhf(0.7978845608028654f * (x + 0.044715f * x3)));
}

// ------------- fp32 tiled GEMM, 128 threads, reg-prefetch staging ----------
// A: [M,K] row-major. B: [K,N] row-major (BT=false) or [N,K] row-major (BT=true).
// EPI==0: C = scale*acc.  EPI==1: C = gelu(acc) * WS[m][n]  (WS is [M,N] rm).
// ZW: block zeroes 1024 floats of WS at offset bid*1024 (requires 256-block
// grid; k1's grid is 256 blocks x 1024 floats = the full 1024x256 wsum).
// Structure per K-tile: {barrier; ds_write(regs); issue global loads for
// tile t+1; barrier; compute}. The prefetched loads fly under the ~1500-cyc
// compute phase, so the next tile's ds_write sees vmcnt already satisfied
// (T14 issue-early/write-late). 2 barriers/tile as in the proven r0 shape.
// Fragments: TN==4 always (ds_read_b128 for B); TM=4 -> b128 for A too
// (0.5 LDS floats per FMA, the DS-bandwidth sweet spot at 2 waves/CU).
template<int BM, int BN, int BK, int TM, int TN, bool BT, int EPI, bool ZW,
         int NTHR>
__global__ __launch_bounds__(NTHR)
void sgemm(const float* __restrict__ A, const float* __restrict__ B,
           float* __restrict__ C, int M, int N, int K, float scale,
           float* __restrict__ WS)
{
    constexpr int TX = BN / TN;            // threads along N
    constexpr int TY = BM / TM;            // threads along M
    static_assert(TX * TY == NTHR, "thread map");
    static_assert(TN == 4, "b128 B-fragment");
    constexpr int NA = (BM * BK / 4) / NTHR;                     // f4/thread A
    constexpr int NB = (BT ? BN * BK : BK * BN) / 4 / NTHR;      // f4/thread B

    __shared__ float As[BK][BM + 4];   // [k][m], +4 keeps rows 16B-aligned
    __shared__ float Bs[BK][BN + 4];
    const int tid = threadIdx.x;
    const int tx  = tid % TX;
    const int ty  = tid / TX;
    const int m0  = blockIdx.y * BM;
    const int n0  = blockIdx.x * BN;

    if (ZW) {
        const int bid = blockIdx.y * gridDim.x + blockIdx.x;
        float4 z = make_float4(0.f, 0.f, 0.f, 0.f);
        *(float4*)(WS + (size_t)bid * 1024 + tid * 8)     = z;
        *(float4*)(WS + (size_t)bid * 1024 + tid * 8 + 4) = z;
    }

    float4 ra[NA], rb[NB];
    auto loadAB = [&](int k0) {
#pragma unroll
        for (int it = 0; it < NA; ++it) {
            int L = tid + NTHR * it;
            int row = L / (BK / 4), kq = L % (BK / 4);
            ra[it] = *(const float4*)(A + (size_t)(m0 + row) * K + k0 + kq * 4);
        }
        if (!BT) {
#pragma unroll
            for (int it = 0; it < NB; ++it) {
                int L = tid + NTHR * it;
                int k = L / (BN / 4), nq = L % (BN / 4);
                rb[it] = *(const float4*)(B + (size_t)(k0 + k) * N + n0 + nq * 4);
            }
        } else {
#pragma unroll
            for (int it = 0; it < NB; ++it) {
                int L = tid + NTHR * it;
                int n = L / (BK / 4), kq = L % (BK / 4);
                rb[it] = *(const float4*)(B + (size_t)(n0 + n) * K + k0 + kq * 4);
            }
        }
    };
    auto storeAB = [&]() {
#pragma unroll
        for (int it = 0; it < NA; ++it) {
            int L = tid + NTHR * it;
            int row = L / (BK / 4), kq = L % (BK / 4);
            As[kq * 4 + 0][row] = ra[it].x; As[kq * 4 + 1][row] = ra[it].y;
            As[kq * 4 + 2][row] = ra[it].z; As[kq * 4 + 3][row] = ra[it].w;
        }
        if (!BT) {
#pragma unroll
            for (int it = 0; it < NB; ++it) {
                int L = tid + NTHR * it;
                int k = L / (BN / 4), nq = L % (BN / 4);
                *(float4*)&Bs[k][nq * 4] = rb[it];
            }
        } else {
#pragma unroll
            for (int it = 0; it < NB; ++it) {
                int L = tid + NTHR * it;
                int n = L / (BK / 4), kq = L % (BK / 4);
                Bs[kq * 4 + 0][n] = rb[it].x; Bs[kq * 4 + 1][n] = rb[it].y;
                Bs[kq * 4 + 2][n] = rb[it].z; Bs[kq * 4 + 3][n] = rb[it].w;
            }
        }
    };

    float acc[TM][TN];
#pragma unroll
    for (int i = 0; i < TM; ++i)
#pragma unroll
        for (int j = 0; j < TN; ++j) acc[i][j] = 0.f;

    loadAB(0);
    for (int k0 = 0; k0 < K; k0 += BK) {
        __syncthreads();                    // consumers of previous tile done
        storeAB();                          // vmcnt satisfied (prefetched)
        if (k0 + BK < K) loadAB(k0 + BK);   // issue-early; hides under compute
        __syncthreads();                    // LDS tile ready
#pragma unroll
        for (int k = 0; k < BK; ++k) {
            float a[TM], b[TN];
            if (TM == 4) {
                float4 av = *(const float4*)&As[k][ty * 4];   // b128 broadcast
                a[0] = av.x; a[1] = av.y; a[2] = av.z; a[3] = av.w;
            } else {
#pragma unroll
                for (int i = 0; i < TM; ++i) a[i] = As[k][ty * TM + i];
            }
            float4 bv = *(const float4*)&Bs[k][tx * 4];       // b128
            b[0] = bv.x; b[1] = bv.y; b[2] = bv.z; b[3] = bv.w;
#pragma unroll
            for (int i = 0; i < TM; ++i)
#pragma unroll
                for (int j = 0; j < TN; ++j) acc[i][j] += a[i] * b[j];
        }
    }

#pragma unroll
    for (int i = 0; i < TM; ++i) {
        int m = m0 + ty * TM + i;
        float4 o;
        if (EPI == 1) {
            float4 w = *(const float4*)(WS + (size_t)m * N + n0 + tx * 4);
            o.x = gelu_t(acc[i][0]) * w.x; o.y = gelu_t(acc[i][1]) * w.y;
            o.z = gelu_t(acc[i][2]) * w.z; o.w = gelu_t(acc[i][3]) * w.w;
        } else {
            o = make_float4(acc[i][0] * scale, acc[i][1] * scale,
                            acc[i][2] * scale, acc[i][3] * scale);
        }
        *(float4*)(C + (size_t)m * N + n0 + tx * 4) = o;
    }
}

// ---------------- wave-uniform top-16 selection helpers ---------------------
// monotone map: f32 -> u32 preserving order (no NaN in inputs)
__device__ __forceinline__ unsigned f2mono(float f)
{
    int b = __float_as_int(f);
    return (unsigned)(b ^ ((b >> 31) | 0x80000000));
}
// count of set bits strictly below my lane
__device__ __forceinline__ int mbcnt64(unsigned long long m)
{
    return __builtin_amdgcn_mbcnt_hi((unsigned)(m >> 32),
           __builtin_amdgcn_mbcnt_lo((unsigned)m, 0));
}

// Find tau = 16th-largest of the wave's 256 keys u[0..3], and need = number
// of tau-equal elements to keep (lowest flat index first). Early exit when a
// threshold selects exactly 16 (then {u >= tau} IS the top-16 and need covers
// all equals). Selection rule at call site:
//   sel = (u > tau) || (u == tau && tie_rank_in_ascending_c < need)
__device__ __forceinline__ void find_tau(const unsigned u[4],
                                         unsigned &tau_o, int &need_o)
{
    unsigned tau = 0u;
    for (int bit = 31; bit >= 0; --bit) {
        unsigned t = tau | (1u << bit);
        int cnt = 0;
#pragma unroll
        for (int j = 0; j < 4; ++j)
            cnt += __popcll(__ballot(u[j] >= t));
        if (cnt >= 16) {
            tau = t;
            if (cnt == 16) break;   // exact: threshold set == top-16
        }
    }
    int n_gt = 0;
#pragma unroll
    for (int j = 0; j < 4; ++j)
        n_gt += __popcll(__ballot(u[j] > tau));
    need_o = 16 - n_gt;
    tau_o  = tau;
}

// ---------------- sim + double top-16 + softmax -> atomic wsum --------------
// Grid: 8 heads x 64 token-groups. Block (256 thr = 4 waves) stages its
// head's p=0 keys (256 rows x 32 f) into LDS ONCE with coalesced 128B-line
// loads, XOR-swizzled (d ^ ((row&7)*4)) so the per-lane row reads are
// conflict-free ds_read_b128 at natural 128B row stride. Each wave processes
// 4 tokens. Lane owns rows {l, l+64, l+128, l+192} (flat index c = row, so
// ascending c == j-major, lane-minor). Stage 2 candidates keep the
// c = lane*4+jj (lane-major) layout from the verified r3 kernel.
__global__ __launch_bounds__(256)
void k_simtopk(const float* __restrict__ q, const float* __restrict__ keys,
               float* __restrict__ wsum)
{
    __shared__ float Ks[NKEYS][32];   // 32 KB, swizzled columns
    __shared__ float Sv[4][16];       // per-wave: member values (c-order)
    __shared__ int   Sc[4][16];       // per-wave: member flat indices (c-order)
    __shared__ float V0[4][16];       // rank-sorted top-16 values
    __shared__ int   I0[4][16];       // rank-sorted top-16 indices

    const int hh   = blockIdx.x & 7;          // head
    const int tg   = blockIdx.x >> 3;         // token group 0..63
    const int tid  = threadIdx.x;
    const int wid  = tid >> 6;
    const int lane = tid & 63;

    // ---- stage keys[hh][r][0][d] -> Ks[r][d ^ ((r&7)*4)], coalesced ----
#pragma unroll
    for (int it = 0; it < 8; ++it) {
        int idx = it * 1024 + tid * 4;        // flat float index
        int r = idx >> 5, d = idx & 31;       // d multiple of 4
        float4 v = *(const float4*)(keys + ((size_t)hh * NKEYS + r) * 2 * DK + d);
        *(float4*)&Ks[r][d ^ ((r & 7) * 4)] = v;
    }
    __syncthreads();

    const int sw = (lane & 7) * 4;            // row&7 == lane&7 for owned rows

    for (int ti = 0; ti < 4; ++ti) {
        const int t = tg * 16 + wid * 4 + ti;

        // wave-uniform q sub-row (p=0 half): cols hh*32 .. hh*32+31
        const float4* qv = (const float4*)(q + (size_t)t * DIM + hh * DK);
        float4 qr[8];
#pragma unroll
        for (int i = 0; i < 8; ++i) qr[i] = qv[i];

        // sims for rows l+64j from LDS (conflict-free swizzled b128 reads)
        float v1[4];
#pragma unroll
        for (int j = 0; j < 4; ++j) {
            const float* kr = &Ks[lane + 64 * j][0];
            float s = 0.f;
#pragma unroll
            for (int d0 = 0; d0 < 8; ++d0) {
                float4 kk = *(const float4*)&kr[(d0 * 4) ^ sw];
                s += kk.x * qr[d0].x + kk.y * qr[d0].y
                   + kk.z * qr[d0].z + kk.w * qr[d0].w;
            }
            v1[j] = s;
        }

        // ---- stage 1: top-16 of sims (tie order: ascending c = j-major) ----
        unsigned u1[4];
#pragma unroll
        for (int j = 0; j < 4; ++j) u1[j] = f2mono(v1[j]);
        unsigned tau1; int need1;
        find_tau(u1, tau1, need1);

        bool sel1[4];
        {
            int pre = 0;
#pragma unroll
            for (int j = 0; j < 4; ++j) {
                bool gt = u1[j] > tau1, eq = u1[j] == tau1;
                unsigned long long bal = __ballot(eq);
                sel1[j] = gt || (eq && (pre + mbcnt64(bal)) < need1);
                pre += __popcll(bal);
            }
        }
        // compact members to LDS in ascending-c (j-major) order
        {
            int pre = 0;
#pragma unroll
            for (int j = 0; j < 4; ++j) {
                unsigned long long bal = __ballot(sel1[j]);
                int pos = pre + mbcnt64(bal);
                if (sel1[j]) { Sv[wid][pos] = v1[j]; Sc[wid][pos] = lane + 64 * j; }
                pre += __popcll(bal);
            }
        }
        __syncthreads();

        // rank each member among the 16 (value desc, tie -> lower index)
        {
            float mv = Sv[wid][lane & 15];
            int   mc = Sc[wid][lane & 15];
            int rank = 0;
#pragma unroll
            for (int k = 0; k < 16; ++k) {
                float ov = Sv[wid][k];
                int   oc = Sc[wid][k];
                rank += (ov > mv || (ov == mv && oc < mc)) ? 1 : 0;
            }
            if (lane < 16) { V0[wid][rank] = mv; I0[wid][rank] = mc; }
        }
        __syncthreads();

        // ---- stage 2: cand(i,j) = v0[i] + i0[j], c = 16i+j = lane*4+jj ----
        const float v0v = V0[wid][lane >> 2];
        const int4  iv  = *(const int4*)&I0[wid][(lane & 3) * 4];
        float f[4];
        f[0] = v0v + (float)iv.x; f[1] = v0v + (float)iv.y;
        f[2] = v0v + (float)iv.z; f[3] = v0v + (float)iv.w;
        unsigned u2[4];
#pragma unroll
        for (int j = 0; j < 4; ++j) u2[j] = f2mono(f[j]);
        unsigned tau2; int need2;
        find_tau(u2, tau2, need2);

        bool sel2[4];
        {
            bool gt2[4], eq2[4];
            int below = 0;
#pragma unroll
            for (int j = 0; j < 4; ++j) {
                gt2[j] = u2[j] > tau2;
                eq2[j] = u2[j] == tau2;
                below += mbcnt64(__ballot(eq2[j]));
            }
            int run = 0;
#pragma unroll
            for (int j = 0; j < 4; ++j) {
                sel2[j] = gt2[j] || (eq2[j] && (below + run) < need2);
                run += eq2[j] ? 1 : 0;
            }
        }

        // global max of candidates = v0[0] + max(i0): lanes {4g..4g+3} hold
        // all 16 i0 entries -> 2-step xor-reduce within each 4-group.
        int mi = max(max(iv.x, iv.y), max(iv.z, iv.w));
        mi = max(mi, __shfl_xor(mi, 1, 64));
        mi = max(mi, __shfl_xor(mi, 2, 64));
        const float mx = V0[wid][0] + (float)mi;

        float e[4];
        float s = 0.f;
#pragma unroll
        for (int j = 0; j < 4; ++j) {
            e[j] = sel2[j] ? expf(f[j] - mx) : 0.f;
            s += e[j];
        }
#pragma unroll
        for (int off = 32; off; off >>= 1) s += __shfl_xor(s, off, 64);
        const float inv = 1.f / s;

#pragma unroll
        for (int j = 0; j < 4; ++j)
            if (sel2[j])
                atomicAdd(&wsum[(size_t)t * NKEYS + lane * 4 + j], e[j] * inv);
    }
}

// ---------------- launch ----------------
extern "C" void kernel_launch(void* const* d_in, const int* in_sizes, int n_in,
                              void* d_out, int out_size, void* d_ws, size_t ws_size,
                              hipStream_t stream)
{
    const float* x    = (const float*)d_in[0];   // [1024, 512]
    const float* wq   = (const float*)d_in[1];   // [512, 512]
    const float* keys = (const float*)d_in[2];   // [8, 256, 2, 32]
    const float* wd   = (const float*)d_in[3];   // [65536, 512] (rows 0..255 used)
    const float* wu   = (const float*)d_in[4];   // [65536, 512] (rows 0..255 used)
    float* out = (float*)d_out;                  // [1024, 512]

    float* q    = (float*)d_ws;                  // 1024*512
    float* Cb   = q + NTOK * DIM;                // 1024*256
    float* wsum = Cb + NTOK * NKEYS;             // 1024*256

    const float bnscale = 1.0f / sqrtf(1.0f + 1e-5f);

    // q = (x @ wq) * bnscale  [1024 x 512], K=512; also zeroes wsum (1KB/blk)
    sgemm<32, 64, 64, 4, 4, false, 0, true, 128>
        <<<dim3(DIM / 64, NTOK / 32), 128, 0, stream>>>(x, wq, q, NTOK, DIM, DIM,
                                                        bnscale, wsum);

    // sim + double top-16 + softmax -> atomic accumulate into wsum[t][e]
    k_simtopk<<<dim3(HEADS * 64), 256, 0, stream>>>(q, keys, wsum);

    // Cb[t,e] = gelu(q . wd[e]) * wsum[t,e]   [1024 x 256], K=512, B^T
    sgemm<32, 32, 64, 2, 4, true, 1, false, 128>
        <<<dim3(NKEYS / 32, NTOK / 32), 128, 0, stream>>>(q, wd, Cb, NTOK, NKEYS,
                                                          DIM, 1.f, wsum);

    // out = Cb @ wu[0:256]   [1024 x 512], K=256
    sgemm<32, 64, 64, 4, 4, false, 0, false, 128>
        <<<dim3(DIM / 64, NTOK / 32), 128, 0, stream>>>(Cb, wu, out, NTOK, DIM,
                                                        NKEYS, 1.f, wsum);
}

// Round 6
// 296.478 us; speedup vs baseline: 1.0233x; 1.0233x over previous
//
#include <hip/hip_runtime.h>
#include <math.h>

#define DIM    512
#define HEADS  8
#define DK     32
#define NKEYS  256
#define PKTOP  16
#define NTOK   1024   // b*n = 2*512

// gelu (tanh approx, matches flax approximate gelu)
__device__ __forceinline__ float gelu_t(float x)
{
    float x3 = x * x * x;
    return 0.5f * x * (1.f + tanhf(0.7978845608028654f * (x + 0.044715f * x3)));
}

// ---------------- generic fp32 tiled GEMM (r4 proven structure + T14) -------
// A: [M,K] row-major. B: [K,N] row-major (BT=false) or [N,K] row-major (BT=true).
// EPI==0: C = scale*acc.  EPI==1: C = gelu(acc) * WS[m][n]  (WS is [M,N] rm).
// ZW: block zeroes 1024 floats of WS at offset bid*1024 (k1 grid is 256
// blocks x 1024 floats = the full 1024x256 wsum).
// ONLY change vs r4 (289.9 us): global->reg loads for tile t+1 are issued
// right after the ds_write of tile t (issue-early / write-late, T14). The
// loads then fly under the ~1500-cyc compute phase, so the next storeAB's
// implicit vmcnt wait is already satisfied. 256 threads (4 waves/CU at
// 1 block/CU) and the 2-barrier-per-tile shape are kept verbatim.
template<int BM, int BN, int BK, int TM, int TN, bool BT, int EPI, bool ZW>
__global__ __launch_bounds__(256)
void sgemm(const float* __restrict__ A, const float* __restrict__ B,
           float* __restrict__ C, int M, int N, int K, float scale,
           float* __restrict__ WS)
{
    constexpr int NA = (BM * BK / 4) / 256;                     // f4/thread A
    constexpr int NB = (BT ? BN * BK : BK * BN) / 4 / 256;      // f4/thread B

    __shared__ float As[BK][BM + 4];
    __shared__ float Bs[BK][BN + 4];
    const int tid = threadIdx.x;
    const int tx  = tid & 15;
    const int ty  = tid >> 4;
    const int m0  = blockIdx.y * BM;
    const int n0  = blockIdx.x * BN;

    if (ZW) {
        const int bid = blockIdx.y * gridDim.x + blockIdx.x;
        *(float4*)(WS + (size_t)bid * 1024 + tid * 4) = make_float4(0.f, 0.f, 0.f, 0.f);
    }

    float4 ra[NA], rb[NB];
    auto loadAB = [&](int k0) {
#pragma unroll
        for (int it = 0; it < NA; ++it) {
            int L = tid + 256 * it;
            int row = L / (BK / 4), kq = L % (BK / 4);
            ra[it] = *(const float4*)(A + (size_t)(m0 + row) * K + k0 + kq * 4);
        }
        if (!BT) {
#pragma unroll
            for (int it = 0; it < NB; ++it) {
                int L = tid + 256 * it;
                int k = L / (BN / 4), nq = L % (BN / 4);
                rb[it] = *(const float4*)(B + (size_t)(k0 + k) * N + n0 + nq * 4);
            }
        } else {
#pragma unroll
            for (int it = 0; it < NB; ++it) {
                int L = tid + 256 * it;
                int n = L / (BK / 4), kq = L % (BK / 4);
                rb[it] = *(const float4*)(B + (size_t)(n0 + n) * K + k0 + kq * 4);
            }
        }
    };
    auto storeAB = [&]() {
#pragma unroll
        for (int it = 0; it < NA; ++it) {
            int L = tid + 256 * it;
            int row = L / (BK / 4), kq = L % (BK / 4);
            As[kq * 4 + 0][row] = ra[it].x; As[kq * 4 + 1][row] = ra[it].y;
            As[kq * 4 + 2][row] = ra[it].z; As[kq * 4 + 3][row] = ra[it].w;
        }
        if (!BT) {
#pragma unroll
            for (int it = 0; it < NB; ++it) {
                int L = tid + 256 * it;
                int k = L / (BN / 4), nq = L % (BN / 4);
                *(float4*)&Bs[k][nq * 4] = rb[it];
            }
        } else {
#pragma unroll
            for (int it = 0; it < NB; ++it) {
                int L = tid + 256 * it;
                int n = L / (BK / 4), kq = L % (BK / 4);
                Bs[kq * 4 + 0][n] = rb[it].x; Bs[kq * 4 + 1][n] = rb[it].y;
                Bs[kq * 4 + 2][n] = rb[it].z; Bs[kq * 4 + 3][n] = rb[it].w;
            }
        }
    };

    float acc[TM][TN];
#pragma unroll
    for (int i = 0; i < TM; ++i)
#pragma unroll
        for (int j = 0; j < TN; ++j) acc[i][j] = 0.f;

    loadAB(0);
    for (int k0 = 0; k0 < K; k0 += BK) {
        __syncthreads();                    // previous tile's consumers done
        storeAB();                          // vmcnt already satisfied (prefetch)
        if (k0 + BK < K) loadAB(k0 + BK);   // issue-early: hides under compute
        __syncthreads();                    // LDS tile ready
#pragma unroll
        for (int k = 0; k < BK; ++k) {
            float a[TM], b[TN];
#pragma unroll
            for (int i = 0; i < TM; ++i) a[i] = As[k][ty * TM + i];
#pragma unroll
            for (int j = 0; j < TN; ++j) b[j] = Bs[k][tx * TN + j];
#pragma unroll
            for (int i = 0; i < TM; ++i)
#pragma unroll
                for (int j = 0; j < TN; ++j) acc[i][j] += a[i] * b[j];
        }
    }
#pragma unroll
    for (int i = 0; i < TM; ++i) {
        int m = m0 + ty * TM + i;
#pragma unroll
        for (int j = 0; j < TN; ++j) {
            int n = n0 + tx * TN + j;
            if (EPI == 1)
                C[(size_t)m * N + n] = gelu_t(acc[i][j]) * WS[(size_t)m * N + n];
            else
                C[(size_t)m * N + n] = acc[i][j] * scale;
        }
    }
}

// ---------------- wave-uniform top-16 selection helpers ---------------------
// monotone map: f32 -> u32 preserving order (no NaN in inputs)
__device__ __forceinline__ unsigned f2mono(float f)
{
    int b = __float_as_int(f);
    return (unsigned)(b ^ ((b >> 31) | 0x80000000));
}
// count of set bits strictly below my lane
__device__ __forceinline__ int mbcnt64(unsigned long long m)
{
    return __builtin_amdgcn_mbcnt_hi((unsigned)(m >> 32),
           __builtin_amdgcn_mbcnt_lo((unsigned)m, 0));
}

// Find tau = 16th-largest of the wave's 256 keys u[0..3], and need = number
// of tau-equal elements to keep (lowest flat index first). Early exit when a
// threshold selects exactly 16 (then {u >= tau} IS the top-16 and need covers
// all equals). Selection rule at call site:
//   sel = (u > tau) || (u == tau && tie_rank_in_ascending_c < need)
__device__ __forceinline__ void find_tau(const unsigned u[4],
                                         unsigned &tau_o, int &need_o)
{
    unsigned tau = 0u;
    for (int bit = 31; bit >= 0; --bit) {
        unsigned t = tau | (1u << bit);
        int cnt = 0;
#pragma unroll
        for (int j = 0; j < 4; ++j)
            cnt += __popcll(__ballot(u[j] >= t));
        if (cnt >= 16) {
            tau = t;
            if (cnt == 16) break;   // exact: threshold set == top-16
        }
    }
    int n_gt = 0;
#pragma unroll
    for (int j = 0; j < 4; ++j)
        n_gt += __popcll(__ballot(u[j] > tau));
    need_o = 16 - n_gt;
    tau_o  = tau;
}

// ---------------- sim + double top-16 + softmax -> atomic wsum --------------
// Grid: 8 heads x 64 token-groups. Block (256 thr = 4 waves) stages its
// head's p=0 keys (256 rows x 32 f) into LDS ONCE with coalesced 128B-line
// loads, XOR-swizzled (d ^ ((row&7)*4)) so the per-lane row reads are
// conflict-free ds_read_b128 at natural 128B row stride. Each wave processes
// 4 tokens. Lane owns rows {l, l+64, l+128, l+192} (flat index c = row, so
// ascending c == j-major, lane-minor). Stage 2 candidates keep the
// c = lane*4+jj (lane-major) layout from the verified r3 kernel.
__global__ __launch_bounds__(256)
void k_simtopk(const float* __restrict__ q, const float* __restrict__ keys,
               float* __restrict__ wsum)
{
    __shared__ float Ks[NKEYS][32];   // 32 KB, swizzled columns
    __shared__ float Sv[4][16];       // per-wave: member values (c-order)
    __shared__ int   Sc[4][16];       // per-wave: member flat indices (c-order)
    __shared__ float V0[4][16];       // rank-sorted top-16 values
    __shared__ int   I0[4][16];       // rank-sorted top-16 indices

    const int hh   = blockIdx.x & 7;          // head
    const int tg   = blockIdx.x >> 3;         // token group 0..63
    const int tid  = threadIdx.x;
    const int wid  = tid >> 6;
    const int lane = tid & 63;

    // ---- stage keys[hh][r][0][d] -> Ks[r][d ^ ((r&7)*4)], coalesced ----
#pragma unroll
    for (int it = 0; it < 8; ++it) {
        int idx = it * 1024 + tid * 4;        // flat float index
        int r = idx >> 5, d = idx & 31;       // d multiple of 4
        float4 v = *(const float4*)(keys + ((size_t)hh * NKEYS + r) * 2 * DK + d);
        *(float4*)&Ks[r][d ^ ((r & 7) * 4)] = v;
    }
    __syncthreads();

    const int sw = (lane & 7) * 4;            // row&7 == lane&7 for owned rows

    for (int ti = 0; ti < 4; ++ti) {
        const int t = tg * 16 + wid * 4 + ti;

        // wave-uniform q sub-row (p=0 half): cols hh*32 .. hh*32+31
        const float4* qv = (const float4*)(q + (size_t)t * DIM + hh * DK);
        float4 qr[8];
#pragma unroll
        for (int i = 0; i < 8; ++i) qr[i] = qv[i];

        // sims for rows l+64j from LDS (conflict-free swizzled b128 reads)
        float v1[4];
#pragma unroll
        for (int j = 0; j < 4; ++j) {
            const float* kr = &Ks[lane + 64 * j][0];
            float s = 0.f;
#pragma unroll
            for (int d0 = 0; d0 < 8; ++d0) {
                float4 kk = *(const float4*)&kr[(d0 * 4) ^ sw];
                s += kk.x * qr[d0].x + kk.y * qr[d0].y
                   + kk.z * qr[d0].z + kk.w * qr[d0].w;
            }
            v1[j] = s;
        }

        // ---- stage 1: top-16 of sims (tie order: ascending c = j-major) ----
        unsigned u1[4];
#pragma unroll
        for (int j = 0; j < 4; ++j) u1[j] = f2mono(v1[j]);
        unsigned tau1; int need1;
        find_tau(u1, tau1, need1);

        bool sel1[4];
        {
            int pre = 0;
#pragma unroll
            for (int j = 0; j < 4; ++j) {
                bool gt = u1[j] > tau1, eq = u1[j] == tau1;
                unsigned long long bal = __ballot(eq);
                sel1[j] = gt || (eq && (pre + mbcnt64(bal)) < need1);
                pre += __popcll(bal);
            }
        }
        // compact members to LDS in ascending-c (j-major) order
        {
            int pre = 0;
#pragma unroll
            for (int j = 0; j < 4; ++j) {
                unsigned long long bal = __ballot(sel1[j]);
                int pos = pre + mbcnt64(bal);
                if (sel1[j]) { Sv[wid][pos] = v1[j]; Sc[wid][pos] = lane + 64 * j; }
                pre += __popcll(bal);
            }
        }
        __syncthreads();

        // rank each member among the 16 (value desc, tie -> lower index)
        {
            float mv = Sv[wid][lane & 15];
            int   mc = Sc[wid][lane & 15];
            int rank = 0;
#pragma unroll
            for (int k = 0; k < 16; ++k) {
                float ov = Sv[wid][k];
                int   oc = Sc[wid][k];
                rank += (ov > mv || (ov == mv && oc < mc)) ? 1 : 0;
            }
            if (lane < 16) { V0[wid][rank] = mv; I0[wid][rank] = mc; }
        }
        __syncthreads();

        // ---- stage 2: cand(i,j) = v0[i] + i0[j], c = 16i+j = lane*4+jj ----
        const float v0v = V0[wid][lane >> 2];
        const int4  iv  = *(const int4*)&I0[wid][(lane & 3) * 4];
        float f[4];
        f[0] = v0v + (float)iv.x; f[1] = v0v + (float)iv.y;
        f[2] = v0v + (float)iv.z; f[3] = v0v + (float)iv.w;
        unsigned u2[4];
#pragma unroll
        for (int j = 0; j < 4; ++j) u2[j] = f2mono(f[j]);
        unsigned tau2; int need2;
        find_tau(u2, tau2, need2);

        bool sel2[4];
        {
            bool gt2[4], eq2[4];
            int below = 0;
#pragma unroll
            for (int j = 0; j < 4; ++j) {
                gt2[j] = u2[j] > tau2;
                eq2[j] = u2[j] == tau2;
                below += mbcnt64(__ballot(eq2[j]));
            }
            int run = 0;
#pragma unroll
            for (int j = 0; j < 4; ++j) {
                sel2[j] = gt2[j] || (eq2[j] && (below + run) < need2);
                run += eq2[j] ? 1 : 0;
            }
        }

        // global max of candidates = v0[0] + max(i0): lanes {4g..4g+3} hold
        // all 16 i0 entries -> 2-step xor-reduce within each 4-group.
        int mi = max(max(iv.x, iv.y), max(iv.z, iv.w));
        mi = max(mi, __shfl_xor(mi, 1, 64));
        mi = max(mi, __shfl_xor(mi, 2, 64));
        const float mx = V0[wid][0] + (float)mi;

        float e[4];
        float s = 0.f;
#pragma unroll
        for (int j = 0; j < 4; ++j) {
            e[j] = sel2[j] ? expf(f[j] - mx) : 0.f;
            s += e[j];
        }
#pragma unroll
        for (int off = 32; off; off >>= 1) s += __shfl_xor(s, off, 64);
        const float inv = 1.f / s;

#pragma unroll
        for (int j = 0; j < 4; ++j)
            if (sel2[j])
                atomicAdd(&wsum[(size_t)t * NKEYS + lane * 4 + j], e[j] * inv);
    }
}

// ---------------- launch ----------------
extern "C" void kernel_launch(void* const* d_in, const int* in_sizes, int n_in,
                              void* d_out, int out_size, void* d_ws, size_t ws_size,
                              hipStream_t stream)
{
    const float* x    = (const float*)d_in[0];   // [1024, 512]
    const float* wq   = (const float*)d_in[1];   // [512, 512]
    const float* keys = (const float*)d_in[2];   // [8, 256, 2, 32]
    const float* wd   = (const float*)d_in[3];   // [65536, 512] (rows 0..255 used)
    const float* wu   = (const float*)d_in[4];   // [65536, 512] (rows 0..255 used)
    float* out = (float*)d_out;                  // [1024, 512]

    float* q    = (float*)d_ws;                  // 1024*512
    float* Cb   = q + NTOK * DIM;                // 1024*256
    float* wsum = Cb + NTOK * NKEYS;             // 1024*256

    const float bnscale = 1.0f / sqrtf(1.0f + 1e-5f);

    // q = (x @ wq) * bnscale  [1024 x 512], K=512; also zeroes wsum (1KB/blk)
    sgemm<32, 64, 64, 2, 4, false, 0, true>
        <<<dim3(DIM / 64, NTOK / 32), 256, 0, stream>>>(x, wq, q, NTOK, DIM, DIM,
                                                        bnscale, wsum);

    // sim + double top-16 + softmax -> atomic accumulate into wsum[t][e]
    k_simtopk<<<dim3(HEADS * 64), 256, 0, stream>>>(q, keys, wsum);

    // Cb[t,e] = gelu(q . wd[e]) * wsum[t,e]   [1024 x 256], K=512, B^T
    sgemm<32, 32, 64, 2, 2, true, 1, false>
        <<<dim3(NKEYS / 32, NTOK / 32), 256, 0, stream>>>(q, wd, Cb, NTOK, NKEYS,
                                                          DIM, 1.f, wsum);

    // out = Cb @ wu[0:256]   [1024 x 512], K=256
    sgemm<32, 64, 64, 2, 4, false, 0, false>
        <<<dim3(DIM / 64, NTOK / 32), 256, 0, stream>>>(Cb, wu, out, NTOK, DIM,
                                                        NKEYS, 1.f, wsum);
}

// Round 7
// 289.111 us; speedup vs baseline: 1.0494x; 1.0255x over previous
//
#include <hip/hip_runtime.h>
#include <math.h>

#define DIM    512
#define HEADS  8
#define DK     32
#define NKEYS  256
#define PKTOP  16
#define NTOK   1024   // b*n = 2*512

// gelu (tanh approx, matches flax approximate gelu)
__device__ __forceinline__ float gelu_t(float x)
{
    float x3 = x * x * x;
    return 0.5f * x * (1.f + tanhf(0.7978845608028654f * (x + 0.044715f * x3)));
}

// ---------------- generic fp32 tiled GEMM (proven best: 289.9 us) -----------
// A: [M,K] row-major. B: [K,N] row-major (BT=false) or [N,K] row-major (BT=true).
// EPI==0: C = scale*acc.  EPI==1: C = gelu(acc) * WS[m][n]  (WS is [M,N] rm).
// ZW: block zeroes 1024 floats of WS at offset bid*1024 (k1 grid is 256
// blocks x 1024 floats = the full 1024x256 wsum).
// NOTE: direct inline staging with 2 barriers/tile. Three pipelining variants
// (wave-K-split r1, TM4+prefetch r5, prefetch-only r6) all measured SLOWER —
// 4 waves/CU already hide staging latency via implicit wave-level overlap;
// holding prefetch registers across compute costs more than it hides.
template<int BM, int BN, int BK, int TM, int TN, bool BT, int EPI, bool ZW>
__global__ __launch_bounds__(256)
void sgemm(const float* __restrict__ A, const float* __restrict__ B,
           float* __restrict__ C, int M, int N, int K, float scale,
           float* __restrict__ WS)
{
    __shared__ float As[BK][BM + 4];
    __shared__ float Bs[BK][BN + 4];
    const int tid = threadIdx.x;
    const int tx  = tid & 15;
    const int ty  = tid >> 4;
    const int m0  = blockIdx.y * BM;
    const int n0  = blockIdx.x * BN;

    if (ZW) {
        const int bid = blockIdx.y * gridDim.x + blockIdx.x;
        *(float4*)(WS + (size_t)bid * 1024 + tid * 4) = make_float4(0.f, 0.f, 0.f, 0.f);
    }

    float acc[TM][TN];
#pragma unroll
    for (int i = 0; i < TM; ++i)
#pragma unroll
        for (int j = 0; j < TN; ++j) acc[i][j] = 0.f;

    for (int k0 = 0; k0 < K; k0 += BK) {
        // stage A tile (transposed): As[k][m] = A[m0+m][k0+k]
#pragma unroll
        for (int it = 0; it < (BM * BK / 4) / 256; ++it) {
            int L   = tid + 256 * it;
            int row = L / (BK / 4), kq = L % (BK / 4);
            float4 v = *(const float4*)(A + (size_t)(m0 + row) * K + k0 + kq * 4);
            As[kq * 4 + 0][row] = v.x; As[kq * 4 + 1][row] = v.y;
            As[kq * 4 + 2][row] = v.z; As[kq * 4 + 3][row] = v.w;
        }
        if (!BT) {
#pragma unroll
            for (int it = 0; it < (BK * BN / 4) / 256; ++it) {
                int L = tid + 256 * it;
                int k = L / (BN / 4), nq = L % (BN / 4);
                float4 v = *(const float4*)(B + (size_t)(k0 + k) * N + n0 + nq * 4);
                *(float4*)&Bs[k][nq * 4] = v;
            }
        } else {
#pragma unroll
            for (int it = 0; it < (BN * BK / 4) / 256; ++it) {
                int L = tid + 256 * it;
                int n = L / (BK / 4), kq = L % (BK / 4);
                float4 v = *(const float4*)(B + (size_t)(n0 + n) * K + k0 + kq * 4);
                Bs[kq * 4 + 0][n] = v.x; Bs[kq * 4 + 1][n] = v.y;
                Bs[kq * 4 + 2][n] = v.z; Bs[kq * 4 + 3][n] = v.w;
            }
        }
        __syncthreads();
#pragma unroll
        for (int k = 0; k < BK; ++k) {
            float a[TM], b[TN];
#pragma unroll
            for (int i = 0; i < TM; ++i) a[i] = As[k][ty * TM + i];
#pragma unroll
            for (int j = 0; j < TN; ++j) b[j] = Bs[k][tx * TN + j];
#pragma unroll
            for (int i = 0; i < TM; ++i)
#pragma unroll
                for (int j = 0; j < TN; ++j) acc[i][j] += a[i] * b[j];
        }
        __syncthreads();
    }
#pragma unroll
    for (int i = 0; i < TM; ++i) {
        int m = m0 + ty * TM + i;
#pragma unroll
        for (int j = 0; j < TN; ++j) {
            int n = n0 + tx * TN + j;
            if (EPI == 1)
                C[(size_t)m * N + n] = gelu_t(acc[i][j]) * WS[(size_t)m * N + n];
            else
                C[(size_t)m * N + n] = acc[i][j] * scale;
        }
    }
}

// ---------------- wave-uniform top-16 selection helpers ---------------------
// monotone map: f32 -> u32 preserving order (no NaN in inputs)
__device__ __forceinline__ unsigned f2mono(float f)
{
    int b = __float_as_int(f);
    return (unsigned)(b ^ ((b >> 31) | 0x80000000));
}
// count of set bits strictly below my lane
__device__ __forceinline__ int mbcnt64(unsigned long long m)
{
    return __builtin_amdgcn_mbcnt_hi((unsigned)(m >> 32),
           __builtin_amdgcn_mbcnt_lo((unsigned)m, 0));
}

// Find tau = 16th-largest of the wave's 256 keys u[0..3], and need = number
// of tau-equal elements to keep (lowest flat index first). Early exit when a
// threshold selects exactly 16 (then {u >= tau} IS the top-16 and need covers
// all equals). Selection rule at call site:
//   sel = (u > tau) || (u == tau && tie_rank_in_ascending_c < need)
__device__ __forceinline__ void find_tau(const unsigned u[4],
                                         unsigned &tau_o, int &need_o)
{
    unsigned tau = 0u;
    for (int bit = 31; bit >= 0; --bit) {
        unsigned t = tau | (1u << bit);
        int cnt = 0;
#pragma unroll
        for (int j = 0; j < 4; ++j)
            cnt += __popcll(__ballot(u[j] >= t));
        if (cnt >= 16) {
            tau = t;
            if (cnt == 16) break;   // exact: threshold set == top-16
        }
    }
    int n_gt = 0;
#pragma unroll
    for (int j = 0; j < 4; ++j)
        n_gt += __popcll(__ballot(u[j] > tau));
    need_o = 16 - n_gt;
    tau_o  = tau;
}

// ---------------- sim + double top-16 + softmax -> atomic wsum --------------
// Grid: 8 heads x 64 token-groups. Block (256 thr = 4 waves) stages its
// head's p=0 keys (256 rows x 32 f) into LDS ONCE with coalesced 128B-line
// loads, XOR-swizzled (d ^ ((row&7)*4)) so the per-lane row reads are
// conflict-free ds_read_b128 at natural 128B row stride. Each wave processes
// 4 tokens. Lane owns rows {l, l+64, l+128, l+192} (flat index c = row, so
// ascending c == j-major, lane-minor). Stage 2 candidates keep the
// c = lane*4+jj (lane-major) layout from the verified r3 kernel.
__global__ __launch_bounds__(256)
void k_simtopk(const float* __restrict__ q, const float* __restrict__ keys,
               float* __restrict__ wsum)
{
    __shared__ float Ks[NKEYS][32];   // 32 KB, swizzled columns
    __shared__ float Sv[4][16];       // per-wave: member values (c-order)
    __shared__ int   Sc[4][16];       // per-wave: member flat indices (c-order)
    __shared__ float V0[4][16];       // rank-sorted top-16 values
    __shared__ int   I0[4][16];       // rank-sorted top-16 indices

    const int hh   = blockIdx.x & 7;          // head
    const int tg   = blockIdx.x >> 3;         // token group 0..63
    const int tid  = threadIdx.x;
    const int wid  = tid >> 6;
    const int lane = tid & 63;

    // ---- stage keys[hh][r][0][d] -> Ks[r][d ^ ((r&7)*4)], coalesced ----
#pragma unroll
    for (int it = 0; it < 8; ++it) {
        int idx = it * 1024 + tid * 4;        // flat float index
        int r = idx >> 5, d = idx & 31;       // d multiple of 4
        float4 v = *(const float4*)(keys + ((size_t)hh * NKEYS + r) * 2 * DK + d);
        *(float4*)&Ks[r][d ^ ((r & 7) * 4)] = v;
    }
    __syncthreads();

    const int sw = (lane & 7) * 4;            // row&7 == lane&7 for owned rows

    for (int ti = 0; ti < 4; ++ti) {
        const int t = tg * 16 + wid * 4 + ti;

        // wave-uniform q sub-row (p=0 half): cols hh*32 .. hh*32+31
        const float4* qv = (const float4*)(q + (size_t)t * DIM + hh * DK);
        float4 qr[8];
#pragma unroll
        for (int i = 0; i < 8; ++i) qr[i] = qv[i];

        // sims for rows l+64j from LDS (conflict-free swizzled b128 reads)
        float v1[4];
#pragma unroll
        for (int j = 0; j < 4; ++j) {
            const float* kr = &Ks[lane + 64 * j][0];
            float s = 0.f;
#pragma unroll
            for (int d0 = 0; d0 < 8; ++d0) {
                float4 kk = *(const float4*)&kr[(d0 * 4) ^ sw];
                s += kk.x * qr[d0].x + kk.y * qr[d0].y
                   + kk.z * qr[d0].z + kk.w * qr[d0].w;
            }
            v1[j] = s;
        }

        // ---- stage 1: top-16 of sims (tie order: ascending c = j-major) ----
        unsigned u1[4];
#pragma unroll
        for (int j = 0; j < 4; ++j) u1[j] = f2mono(v1[j]);
        unsigned tau1; int need1;
        find_tau(u1, tau1, need1);

        bool sel1[4];
        {
            int pre = 0;
#pragma unroll
            for (int j = 0; j < 4; ++j) {
                bool gt = u1[j] > tau1, eq = u1[j] == tau1;
                unsigned long long bal = __ballot(eq);
                sel1[j] = gt || (eq && (pre + mbcnt64(bal)) < need1);
                pre += __popcll(bal);
            }
        }
        // compact members to LDS in ascending-c (j-major) order
        {
            int pre = 0;
#pragma unroll
            for (int j = 0; j < 4; ++j) {
                unsigned long long bal = __ballot(sel1[j]);
                int pos = pre + mbcnt64(bal);
                if (sel1[j]) { Sv[wid][pos] = v1[j]; Sc[wid][pos] = lane + 64 * j; }
                pre += __popcll(bal);
            }
        }
        __syncthreads();

        // rank each member among the 16 (value desc, tie -> lower index)
        {
            float mv = Sv[wid][lane & 15];
            int   mc = Sc[wid][lane & 15];
            int rank = 0;
#pragma unroll
            for (int k = 0; k < 16; ++k) {
                float ov = Sv[wid][k];
                int   oc = Sc[wid][k];
                rank += (ov > mv || (ov == mv && oc < mc)) ? 1 : 0;
            }
            if (lane < 16) { V0[wid][rank] = mv; I0[wid][rank] = mc; }
        }
        __syncthreads();

        // ---- stage 2: cand(i,j) = v0[i] + i0[j], c = 16i+j = lane*4+jj ----
        const float v0v = V0[wid][lane >> 2];
        const int4  iv  = *(const int4*)&I0[wid][(lane & 3) * 4];
        float f[4];
        f[0] = v0v + (float)iv.x; f[1] = v0v + (float)iv.y;
        f[2] = v0v + (float)iv.z; f[3] = v0v + (float)iv.w;
        unsigned u2[4];
#pragma unroll
        for (int j = 0; j < 4; ++j) u2[j] = f2mono(f[j]);
        unsigned tau2; int need2;
        find_tau(u2, tau2, need2);

        bool sel2[4];
        {
            bool gt2[4], eq2[4];
            int below = 0;
#pragma unroll
            for (int j = 0; j < 4; ++j) {
                gt2[j] = u2[j] > tau2;
                eq2[j] = u2[j] == tau2;
                below += mbcnt64(__ballot(eq2[j]));
            }
            int run = 0;
#pragma unroll
            for (int j = 0; j < 4; ++j) {
                sel2[j] = gt2[j] || (eq2[j] && (below + run) < need2);
                run += eq2[j] ? 1 : 0;
            }
        }

        // global max of candidates = v0[0] + max(i0): lanes {4g..4g+3} hold
        // all 16 i0 entries -> 2-step xor-reduce within each 4-group.
        int mi = max(max(iv.x, iv.y), max(iv.z, iv.w));
        mi = max(mi, __shfl_xor(mi, 1, 64));
        mi = max(mi, __shfl_xor(mi, 2, 64));
        const float mx = V0[wid][0] + (float)mi;

        float e[4];
        float s = 0.f;
#pragma unroll
        for (int j = 0; j < 4; ++j) {
            e[j] = sel2[j] ? expf(f[j] - mx) : 0.f;
            s += e[j];
        }
#pragma unroll
        for (int off = 32; off; off >>= 1) s += __shfl_xor(s, off, 64);
        const float inv = 1.f / s;

#pragma unroll
        for (int j = 0; j < 4; ++j)
            if (sel2[j])
                atomicAdd(&wsum[(size_t)t * NKEYS + lane * 4 + j], e[j] * inv);
    }
}

// ---------------- launch ----------------
extern "C" void kernel_launch(void* const* d_in, const int* in_sizes, int n_in,
                              void* d_out, int out_size, void* d_ws, size_t ws_size,
                              hipStream_t stream)
{
    const float* x    = (const float*)d_in[0];   // [1024, 512]
    const float* wq   = (const float*)d_in[1];   // [512, 512]
    const float* keys = (const float*)d_in[2];   // [8, 256, 2, 32]
    const float* wd   = (const float*)d_in[3];   // [65536, 512] (rows 0..255 used)
    const float* wu   = (const float*)d_in[4];   // [65536, 512] (rows 0..255 used)
    float* out = (float*)d_out;                  // [1024, 512]

    float* q    = (float*)d_ws;                  // 1024*512
    float* Cb   = q + NTOK * DIM;                // 1024*256
    float* wsum = Cb + NTOK * NKEYS;             // 1024*256

    const float bnscale = 1.0f / sqrtf(1.0f + 1e-5f);

    // q = (x @ wq) * bnscale  [1024 x 512], K=512; also zeroes wsum (1KB/blk)
    sgemm<32, 64, 64, 2, 4, false, 0, true>
        <<<dim3(DIM / 64, NTOK / 32), 256, 0, stream>>>(x, wq, q, NTOK, DIM, DIM,
                                                        bnscale, wsum);

    // sim + double top-16 + softmax -> atomic accumulate into wsum[t][e]
    k_simtopk<<<dim3(HEADS * 64), 256, 0, stream>>>(q, keys, wsum);

    // Cb[t,e] = gelu(q . wd[e]) * wsum[t,e]   [1024 x 256], K=512, B^T
    sgemm<32, 32, 64, 2, 2, true, 1, false>
        <<<dim3(NKEYS / 32, NTOK / 32), 256, 0, stream>>>(q, wd, Cb, NTOK, NKEYS,
                                                          DIM, 1.f, wsum);

    // out = Cb @ wu[0:256]   [1024 x 512], K=256
    sgemm<32, 64, 64, 2, 4, false, 0, false>
        <<<dim3(DIM / 64, NTOK / 32), 256, 0, stream>>>(Cb, wu, out, NTOK, DIM,
                                                        NKEYS, 1.f, wsum);
}